// Round 1
// baseline (80.134 us; speedup 1.0000x reference)
//
#include <hip/hip_runtime.h>
#include <math.h>

#define NQ 9
#define NREPS 2
#define NB 512            // 2^NQ amplitudes
#define NSIMS (16*28*28)  // 12544

// ---- precomputed per-call tables (weight-dependent only, same for all sims)
__device__ float g_cosT[NB];
__device__ float g_sinT[NB];
__device__ int   g_v[NB];

// sigma = composed CNOT-ring permutation source-index map:
// state_out[b] = state_in[sigma(b)]; apply g_{c=8,t=0} first, ... g_{c=0,t=1} last.
// qubit q lives at bit position (NQ-1-q).
__device__ __forceinline__ int sigma9(int b) {
    #pragma unroll
    for (int c = NQ - 1; c >= 0; --c) {
        const int t  = (c + 1) % NQ;
        const int pc = NQ - 1 - c;
        const int pt = NQ - 1 - t;
        b ^= ((b >> pc) & 1) << pt;
    }
    return b;
}

// One block of 512 threads. w = weights[NREPS][NQ].
// final[b] = m(v) * exp(i*Theta(b)), v = sigma^NREPS(b)
// Theta(b) = sum_l phi_l(sigma^{NREPS-l}(b)) - (pi/2)*popcount(v)
__global__ void quanv_setup(const float* __restrict__ w) {
    const int b = threadIdx.x;
    if (b >= NB) return;
    float th = 0.f;
    int cur = b;
    #pragma unroll
    for (int l = NREPS - 1; l >= 0; --l) {
        cur = sigma9(cur);
        #pragma unroll
        for (int q = 0; q < NQ; ++q) {
            const float wq = 0.5f * w[l * NQ + q];
            th += ((cur >> (NQ - 1 - q)) & 1) ? wq : -wq;
        }
    }
    const int v = cur;
    th -= 1.5707963267948966f * (float)__popc((unsigned)v);
    g_cosT[b] = cosf(th);
    g_sinT[b] = sinf(th);
    g_v[b]    = v;
}

// One wave (64 lanes) per simulation; lane holds amplitudes b = (r<<6)|lane, r=0..7.
__global__ __launch_bounds__(256) void quanv_main(
    const float* __restrict__ x,   // [16][28][28]
    float* __restrict__ out)       // [16][9][28][28]
{
    const int tid  = blockIdx.x * blockDim.x + threadIdx.x;
    const int lane = threadIdx.x & 63;
    const int sim  = tid >> 6;
    if (sim >= NSIMS) return;
    const int ox  = sim % 28;
    const int oy  = (sim / 28) % 28;
    const int img = sim / 784;

    // 9 patch angles (3x3, pad=1), half-angle cos/sin. All lanes of the wave
    // load the same 9 addresses (wave-broadcast) and compute redundantly.
    float cq[NQ], sq[NQ];
    #pragma unroll
    for (int q = 0; q < NQ; ++q) {
        const int ky = q / 3, kx = q % 3;
        const int y  = oy + ky - 1;
        const int xx = ox + kx - 1;
        float a = 0.f;
        if (y >= 0 && y < 28 && xx >= 0 && xx < 28)
            a = x[img * 784 + y * 28 + xx];
        __sincosf(0.5f * a, &sq[q], &cq[q]);
    }

    // amplitudes
    float fre[8], fim[8];
    #pragma unroll
    for (int r = 0; r < 8; ++r) {
        const int b = (r << 6) | lane;
        const int v = g_v[b];
        float m = 1.f;
        #pragma unroll
        for (int q = 0; q < NQ; ++q)
            m *= ((v >> (NQ - 1 - q)) & 1) ? sq[q] : cq[q];
        fre[r] = m * g_cosT[b];
        fim[r] = m * g_sinT[b];
    }

    // expectations out_i = 2*Im sum_{bit_i=0} conj(f[b]) f[b^mask_i]
    float e[NQ];
    // qubits 3..8: mask bit p = 8-i is a lane bit (0..5).
    // sum over ALL lanes of sign * Im(conj(f)*shfl(f)) equals out_i directly.
    #pragma unroll
    for (int i = 3; i < NQ; ++i) {
        const int p  = NQ - 1 - i;
        const int st = 1 << p;
        const float sign = ((lane >> p) & 1) ? -1.f : 1.f;
        float acc = 0.f;
        #pragma unroll
        for (int r = 0; r < 8; ++r) {
            const float gre = __shfl_xor(fre[r], st);
            const float gim = __shfl_xor(fim[r], st);
            acc += fre[r] * gim - fim[r] * gre;
        }
        e[i] = sign * acc;
    }
    // qubits 0..2: mask bit is a register bit rb = (8-i)-6; pairs within lane.
    #pragma unroll
    for (int i = 0; i < 3; ++i) {
        const int rb = (NQ - 1 - i) - 6;
        float acc = 0.f;
        #pragma unroll
        for (int r = 0; r < 8; ++r) {
            if (!((r >> rb) & 1)) {
                const int r1 = r | (1 << rb);
                acc += fre[r] * fim[r1] - fim[r] * fre[r1];
            }
        }
        e[i] = 2.f * acc;  // wave-sum gives Im z; out = 2*Im z
    }

    // butterfly-reduce each of the 9 partials across the wave
    #pragma unroll
    for (int i = 0; i < NQ; ++i) {
        float v = e[i];
        #pragma unroll
        for (int st = 32; st >= 1; st >>= 1)
            v += __shfl_xor(v, st);
        e[i] = v;
    }

    if (lane == 0) {
        float* o = out + img * (NQ * 784) + oy * 28 + ox;
        #pragma unroll
        for (int i = 0; i < NQ; ++i)
            o[i * 784] = e[i];
    }
}

extern "C" void kernel_launch(void* const* d_in, const int* in_sizes, int n_in,
                              void* d_out, int out_size, void* d_ws, size_t ws_size,
                              hipStream_t stream) {
    const float* x = (const float*)d_in[0];   // 16*1*28*28 fp32
    const float* w = (const float*)d_in[1];   // NREPS*NQ fp32
    float* out = (float*)d_out;               // 16*9*28*28 fp32
    (void)d_ws; (void)ws_size; (void)in_sizes; (void)n_in; (void)out_size;

    quanv_setup<<<1, NB, 0, stream>>>(w);
    const int waves_per_block = 4;                       // 256 threads
    const int blocks = (NSIMS + waves_per_block - 1) / waves_per_block;  // 3136
    quanv_main<<<blocks, 256, 0, stream>>>(x, out);
}

// Round 2
// 67.579 us; speedup vs baseline: 1.1858x; 1.1858x over previous
//
#include <hip/hip_runtime.h>
#include <math.h>

#define NQ 9
#define NREPS 2
#define NB 512            // 2^NQ amplitudes
#define NSIMS (16*28*28)  // 12544

// ---------------- compile-time linear-algebra of the CNOT ring ----------------
// sigma = source-index permutation of the composed CNOT ring (linear over GF(2)).
__host__ __device__ constexpr int csigma(int b) {
    for (int c = NQ - 1; c >= 0; --c) {
        const int t  = (c + 1) % NQ;
        const int pc = NQ - 1 - c;
        const int pt = NQ - 1 - t;
        b ^= ((b >> pc) & 1) << pt;
    }
    return b;
}
__host__ __device__ constexpr int csig2(int b) { return csigma(csigma(b)); }

// basis images: v(b) = XOR of VB_[k] over set bits k of b
constexpr int VB_[6] = { csig2(1<<0), csig2(1<<1), csig2(1<<2),
                         csig2(1<<3), csig2(1<<4), csig2(1<<5) };
constexpr int VR_[8] = { csig2(0<<6), csig2(1<<6), csig2(2<<6), csig2(3<<6),
                         csig2(4<<6), csig2(5<<6), csig2(6<<6), csig2(7<<6) };

// ---------------- per-call table (weight-dependent only) ----------------
__device__ float2 g_T[NB];   // {cos Theta(b), sin Theta(b)}

__global__ void quanv_setup(const float* __restrict__ w) {
    const int b = threadIdx.x;
    if (b >= NB) return;
    float th = 0.f;
    int cur = b;
    #pragma unroll
    for (int l = NREPS - 1; l >= 0; --l) {
        cur = csigma(cur);
        #pragma unroll
        for (int q = 0; q < NQ; ++q) {
            const float wq = 0.5f * w[l * NQ + q];
            th += ((cur >> (NQ - 1 - q)) & 1) ? wq : -wq;
        }
    }
    th -= 1.5707963267948966f * (float)__popc((unsigned)cur);
    g_T[b] = make_float2(cosf(th), sinf(th));
}

// ---------------- cross-lane helpers ----------------
template<int CTRL>
__device__ __forceinline__ float dppmov(float x) {
    return __int_as_float(__builtin_amdgcn_update_dpp(
        0, __float_as_int(x), CTRL, 0xF, 0xF, true));
}
template<int OFF>
__device__ __forceinline__ float swzx(float x) {
    return __int_as_float(__builtin_amdgcn_ds_swizzle(__float_as_int(x), OFF));
}
// XOR-exchange across lane bit P, cheapest pipe per mask
template<int P>
__device__ __forceinline__ float lane_xor(float x) {
    if constexpr (P == 0) return dppmov<0xB1>(x);      // quad_perm {1,0,3,2}
    else if constexpr (P == 1) return dppmov<0x4E>(x); // quad_perm {2,3,0,1}
    else if constexpr (P == 2) return swzx<0x101F>(x); // ds_swizzle xor 4
    else if constexpr (P == 3) return dppmov<0x128>(x);// row_ror:8 == xor 8
    else if constexpr (P == 4) return swzx<0x401F>(x); // ds_swizzle xor 16
    else return __shfl_xor(x, 32, 64);                 // cross-half
}
// full-wave sum via DPP; result valid in lane 63
__device__ __forceinline__ float wave_reduce(float v) {
    v += dppmov<0x111>(v);  // row_shr:1
    v += dppmov<0x112>(v);  // row_shr:2
    v += dppmov<0x114>(v);  // row_shr:4
    v += dppmov<0x118>(v);  // row_shr:8
    v += dppmov<0x142>(v);  // row_bcast:15
    v += dppmov<0x143>(v);  // row_bcast:31
    return v;
}

// ---------------- main: one wave per simulation ----------------
__global__ __launch_bounds__(256) void quanv_main(
    const float* __restrict__ x,   // [16][28][28]
    float* __restrict__ out)       // [16][9][28][28]
{
    const int tid  = blockIdx.x * blockDim.x + threadIdx.x;
    const int lane = threadIdx.x & 63;
    const int sim  = tid >> 6;          // grid is exact: 3136*4 == 12544
    const int ox  = sim % 28;
    const int oy  = (sim / 28) % 28;
    const int img = sim / 784;

    // 9 patch half-angle cos/sin (wave-redundant; trivially cheap)
    float cq[NQ], sq[NQ];
    #pragma unroll
    for (int q = 0; q < NQ; ++q) {
        const int ky = q / 3, kx = q % 3;
        const int y  = oy + ky - 1;
        const int xx = ox + kx - 1;
        float a = 0.f;
        if (y >= 0 && y < 28 && xx >= 0 && xx < 28)
            a = x[img * 784 + y * 28 + xx];
        __sincosf(0.5f * a, &sq[q], &cq[q]);
    }

    // lane part of v = sigma^2(b):  v = VR_[r] ^ VL
    const int VL = ((lane & 1)  ? VB_[0] : 0) ^ ((lane & 2)  ? VB_[1] : 0)
                 ^ ((lane & 4)  ? VB_[2] : 0) ^ ((lane & 8)  ? VB_[3] : 0)
                 ^ ((lane & 16) ? VB_[4] : 0) ^ ((lane & 32) ? VB_[5] : 0);

    // P0[q] = factor when VR bit q is 0, P1[q] = flipped (VR bits are constexpr)
    float P0[NQ], P1[NQ];
    #pragma unroll
    for (int q = 0; q < NQ; ++q) {
        const bool bit = (VL >> (NQ - 1 - q)) & 1;
        P0[q] = bit ? sq[q] : cq[q];
        P1[q] = bit ? cq[q] : sq[q];
    }

    // amplitudes: f[b] = m * exp(i Theta(b)),  b = (r<<6)|lane
    float fre[8], fim[8];
    #pragma unroll
    for (int r = 0; r < 8; ++r) {
        float m = ((VR_[r] >> (NQ - 1)) & 1) ? P1[0] : P0[0];
        #pragma unroll
        for (int q = 1; q < NQ; ++q)
            m *= ((VR_[r] >> (NQ - 1 - q)) & 1) ? P1[q] : P0[q];
        const float2 T = g_T[(r << 6) | lane];
        fre[r] = m * T.x;
        fim[r] = m * T.y;
    }

    // expectations out_i = 2*Im sum_{bit_i=0} conj(f[b]) f[b^mask_i]
    float e[NQ];
    // lane-bit qubits i=3..8 (mask bit P = 8-i): signed sum over ALL lanes
#define EXP_QUBIT(i, P)                                            \
    {                                                              \
        const float sign = ((lane >> (P)) & 1) ? -1.f : 1.f;       \
        float acc = 0.f;                                           \
        _Pragma("unroll")                                          \
        for (int r = 0; r < 8; ++r) {                              \
            const float gre = lane_xor<P>(fre[r]);                 \
            const float gim = lane_xor<P>(fim[r]);                 \
            acc += fre[r] * gim - fim[r] * gre;                    \
        }                                                          \
        e[i] = sign * acc;                                         \
    }
    EXP_QUBIT(8, 0)
    EXP_QUBIT(7, 1)
    EXP_QUBIT(6, 2)
    EXP_QUBIT(5, 3)
    EXP_QUBIT(4, 4)
    EXP_QUBIT(3, 5)
#undef EXP_QUBIT

    // register-bit qubits i=0..2 (mask bit rb = (8-i)-6): pairs within lane
    #pragma unroll
    for (int i = 0; i < 3; ++i) {
        const int rb = (NQ - 1 - i) - 6;
        float acc = 0.f;
        #pragma unroll
        for (int r = 0; r < 8; ++r) {
            if (!((r >> rb) & 1)) {
                const int r1 = r | (1 << rb);
                acc += fre[r] * fim[r1] - fim[r] * fre[r1];
            }
        }
        e[i] = 2.f * acc;
    }

    // reduce the 9 partials across the wave (DPP, lane 63 holds the sums)
    #pragma unroll
    for (int i = 0; i < NQ; ++i)
        e[i] = wave_reduce(e[i]);

    if (lane == 63) {
        float* o = out + img * (NQ * 784) + oy * 28 + ox;
        #pragma unroll
        for (int i = 0; i < NQ; ++i)
            o[i * 784] = e[i];
    }
}

extern "C" void kernel_launch(void* const* d_in, const int* in_sizes, int n_in,
                              void* d_out, int out_size, void* d_ws, size_t ws_size,
                              hipStream_t stream) {
    const float* x = (const float*)d_in[0];   // 16*1*28*28 fp32
    const float* w = (const float*)d_in[1];   // NREPS*NQ fp32
    float* out = (float*)d_out;               // 16*9*28*28 fp32
    (void)d_ws; (void)ws_size; (void)in_sizes; (void)n_in; (void)out_size;

    quanv_setup<<<1, NB, 0, stream>>>(w);
    quanv_main<<<NSIMS / 4, 256, 0, stream>>>(x, out);  // 4 waves/block
}